// Round 1
// 703.755 us; speedup vs baseline: 1.0385x; 1.0385x over previous
//
#include <hip/hip_runtime.h>

// Problem: B=32, C=256, H=W=64, N=4096, R=16.
// out = (w_w @ softmax(x@x^T/16 + w1@w2^T)) @ conv3x3(x_mid, g_w)
// Round 4: conv_mfma gets async-STAGE split (reg prefetch of next cib issued
// before compute, LDS write after barrier -> HBM latency hidden under MFMA);
// halo zeroing hoisted out of the K loop. sim GEMM gets 4-way K-split with
// partials in d_out, summed in softmax (occupancy 2 -> 8 waves/CU).

#define NB 32
#define NC 256
#define NPIX 4096   // 64*64
#define KSPLIT 4    // sim GEMM K-split factor

typedef __attribute__((ext_vector_type(8))) short short8;
typedef __attribute__((ext_vector_type(16))) float floatx16;

__device__ inline short f2bf(float f) {
    union { float f; unsigned u; } v; v.f = f;
    unsigned r = v.u + 0x7fffu + ((v.u >> 16) & 1u);   // RNE
    return (short)(r >> 16);
}

// ---------------- random_map = w1 @ w2^T  [256,256] ----------------
__global__ __launch_bounds__(256) void rm_kernel(const float* __restrict__ w1,
                                                 const float* __restrict__ w2,
                                                 float* __restrict__ rm) {
    int idx = blockIdx.x * 256 + threadIdx.x;
    int c = idx >> 8, d = idx & 255;
    float s = 0.f;
#pragma unroll
    for (int r = 0; r < 16; r++) s += w1[c * 16 + r] * w2[d * 16 + r];
    rm[idx] = s;
}

// ---------------- generic fp32 -> bf16 (same layout), 8 elems/thread --------
__global__ __launch_bounds__(256) void cvt_bf16_kernel(const float* __restrict__ in,
                                                       short* __restrict__ out) {
    size_t i = ((size_t)blockIdx.x * 256 + threadIdx.x) * 8;
    float4 v0 = *(const float4*)&in[i];
    float4 v1 = *(const float4*)&in[i + 4];
    short8 s;
    s[0] = f2bf(v0.x); s[1] = f2bf(v0.y); s[2] = f2bf(v0.z); s[3] = f2bf(v0.w);
    s[4] = f2bf(v1.x); s[5] = f2bf(v1.y); s[6] = f2bf(v1.z); s[7] = f2bf(v1.w);
    *(short8*)&out[i] = s;
}

// ---------------- x_mid NCHW fp32 -> xt NHWC bf16 [b][h][w][ci] -------------
__global__ __launch_bounds__(256) void cvt_x_kernel(const float* __restrict__ x,
                                                    short* __restrict__ xt) {
    const int h = blockIdx.x;   // 64
    const int b = blockIdx.y;   // 32
    __shared__ short xls[64 * 256];   // [w][ci]
    const int tid = threadIdx.x;
    for (int i = tid; i < 4096; i += 256) {
        int ci = i >> 4, w4 = (i & 15) << 2;
        float4 v = *(const float4*)&x[(((size_t)(b * 256 + ci)) * 64 + h) * 64 + w4];
        xls[(w4 + 0) * 256 + ci] = f2bf(v.x);
        xls[(w4 + 1) * 256 + ci] = f2bf(v.y);
        xls[(w4 + 2) * 256 + ci] = f2bf(v.z);
        xls[(w4 + 3) * 256 + ci] = f2bf(v.w);
    }
    __syncthreads();
    uint4* dst = (uint4*)&xt[(((size_t)(b * 64 + h)) * 64) * 256];
    const uint4* src = (const uint4*)xls;
    for (int i = tid; i < 2048; i += 256) dst[i] = src[i];
}

// ------ g_w [co][ci][3][3] fp32 -> wt fragment-ordered bf16 -----------------
// wt[co_t(4)][ci_b(16)][tap(9)][ch(2)][ls(64)][j(8)]:
//   co = co_t*64 + ch*32 + (ls&31), ci = ci_b*16 + (ls>>5)*8 + j
__global__ __launch_bounds__(256) void cvt_w_kernel(const float* __restrict__ g_w,
                                                    short* __restrict__ wt) {
    int o = blockIdx.x * 256 + threadIdx.x;   // 73728 total (each = 8 bf16)
    if (o >= 73728) return;
    int co_t = o / 18432;
    int rem  = o - co_t * 18432;
    int ci_b = rem / 1152;
    int rem2 = rem - ci_b * 1152;
    int tap  = rem2 / 128;
    int rem3 = rem2 - tap * 128;
    int ch   = rem3 >> 6, ls = rem3 & 63;
    int co = co_t * 64 + ch * 32 + (ls & 31);
    int ci0 = ci_b * 16 + (ls >> 5) * 8;
    short8 v;
#pragma unroll
    for (int j = 0; j < 8; j++)
        v[j] = f2bf(g_w[((size_t)co * 256 + ci0 + j) * 9 + tap]);
    *(short8*)&wt[(size_t)o * 8] = v;
}

// ---------------- conv3x3 via MFMA -> value_t[b][px][co] bf16 ---------------
// A-operand = x patches (m=px), B-operand = weights (n=co); C[px][co].
// Async-STAGE split: global loads of cib+1 issued into registers before the
// compute phase of cib; ds_writes happen after the next barrier (T14).
__global__ __launch_bounds__(256) void conv_mfma(const short* __restrict__ xt,
                                                 const short* __restrict__ wt,
                                                 short* __restrict__ value_t) {
    const int h0  = blockIdx.x * 4;
    const int cot = blockIdx.y;          // co0 = cot*64
    const int b   = blockIdx.z;
    __shared__ short ws[9 * 2 * 64 * 8];     // [tap][ch][ls][8]  18432 B
    __shared__ short xs[6 * 2 * 66 * 8];     // [r][kh2][wx][8]   12672 B
    const int tid = threadIdx.x;
    const int wv = tid >> 6, lane = tid & 63;
    const int kh2 = lane >> 5, ln = lane & 31;

    // ---- per-thread staging geometry (constant over the K loop) ----
    // ws: uint4 indices tid, tid+256, tid+512, tid+768, (tid+1024 if tid<128)
    // xs: uint4 ops tid, tid+256, tid+512 (768 loads); halo (24) hoisted out.
    int xr0, xw0, xh0_, xr1, xw1, xh1_, xr2, xw2, xh2_;
    {
        int i0 = tid;        xr0 = i0 >> 7; int r0 = i0 & 127; xw0 = r0 >> 1; xh0_ = r0 & 1;
        int i1 = tid + 256;  xr1 = i1 >> 7; int r1 = i1 & 127; xw1 = r1 >> 1; xh1_ = r1 & 1;
        int i2 = tid + 512;  xr2 = i2 >> 7; int r2 = i2 & 127; xw2 = r2 >> 1; xh2_ = r2 & 1;
    }
    const int xd0 = (xr0 * 2 + xh0_) * 66 + 1 + xw0;
    const int xd1 = (xr1 * 2 + xh1_) * 66 + 1 + xw1;
    const int xd2 = (xr2 * 2 + xh2_) * 66 + 1 + xw2;
    const int hin0 = h0 - 1 + xr0, hin1 = h0 - 1 + xr1, hin2 = h0 - 1 + xr2;
    const uint4* wsrc_base = (const uint4*)&wt[(size_t)(cot * 16) * 1152 * 8];

    uint4 wr0, wr1, wr2, wr3, wr4;
    uint4 xv0, xv1, xv2;

#define LOAD_CIB(c)                                                            \
    do {                                                                       \
        const uint4* wsrc = wsrc_base + (size_t)(c) * 1152;                    \
        wr0 = wsrc[tid];        wr1 = wsrc[tid + 256];                         \
        wr2 = wsrc[tid + 512];  wr3 = wsrc[tid + 768];                         \
        if (tid < 128) wr4 = wsrc[tid + 1024];                                 \
        xv0 = make_uint4(0, 0, 0, 0); xv1 = xv0; xv2 = xv0;                    \
        if ((unsigned)hin0 < 64u)                                              \
            xv0 = *(const uint4*)&xt[(((size_t)(b * 64 + hin0)) * 64 + xw0) * 256 + (c) * 16 + xh0_ * 8]; \
        if ((unsigned)hin1 < 64u)                                              \
            xv1 = *(const uint4*)&xt[(((size_t)(b * 64 + hin1)) * 64 + xw1) * 256 + (c) * 16 + xh1_ * 8]; \
        if ((unsigned)hin2 < 64u)                                              \
            xv2 = *(const uint4*)&xt[(((size_t)(b * 64 + hin2)) * 64 + xw2) * 256 + (c) * 16 + xh2_ * 8]; \
    } while (0)

#define WRITE_LDS()                                                            \
    do {                                                                       \
        uint4* wdst = (uint4*)ws;                                              \
        wdst[tid] = wr0;        wdst[tid + 256] = wr1;                         \
        wdst[tid + 512] = wr2;  wdst[tid + 768] = wr3;                         \
        if (tid < 128) wdst[tid + 1024] = wr4;                                 \
        uint4* xdst = (uint4*)xs;                                              \
        xdst[xd0] = xv0; xdst[xd1] = xv1; xdst[xd2] = xv2;                     \
    } while (0)

    // halo columns of xs are always zero -> write once, never overwritten
    if (tid < 24) {
        int r = tid >> 2, half = (tid >> 1) & 1, side = tid & 1;
        ((uint4*)xs)[(r * 2 + half) * 66 + side * 65] = make_uint4(0, 0, 0, 0);
    }

    floatx16 acc00 = {}, acc01 = {}, acc10 = {}, acc11 = {};   // [pxh][coh]

    LOAD_CIB(0);
    for (int cib = 0; cib < 16; ++cib) {
        __syncthreads();            // previous compute done reading LDS
        WRITE_LDS();                // waits vmcnt on staged regs only
        if (cib < 15) LOAD_CIB(cib + 1);   // prefetch: in flight across compute
        __syncthreads();            // LDS writes visible

#pragma unroll
        for (int tap = 0; tap < 9; ++tap) {
            const int kh = tap / 3, kw = tap - kh * 3;
            const int r = wv + kh;
            short8 wf0 = *(const short8*)&ws[((tap * 2 + 0) * 64 + lane) * 8];
            short8 wf1 = *(const short8*)&ws[((tap * 2 + 1) * 64 + lane) * 8];
            short8 xf0 = *(const short8*)&xs[(((r * 2 + kh2) * 66) + kw + ln) * 8];
            short8 xf1 = *(const short8*)&xs[(((r * 2 + kh2) * 66) + kw + 32 + ln) * 8];
            acc00 = __builtin_amdgcn_mfma_f32_32x32x16_bf16(xf0, wf0, acc00, 0, 0, 0);
            acc01 = __builtin_amdgcn_mfma_f32_32x32x16_bf16(xf0, wf1, acc01, 0, 0, 0);
            acc10 = __builtin_amdgcn_mfma_f32_32x32x16_bf16(xf1, wf0, acc10, 0, 0, 0);
            acc11 = __builtin_amdgcn_mfma_f32_32x32x16_bf16(xf1, wf1, acc11, 0, 0, 0);
        }
    }
#undef LOAD_CIB
#undef WRITE_LDS

    // C/D: col(lane&31)=co, row=(reg&3)+8*(reg>>2)+4*kh2 = px within 32-tile
    const int h_out = h0 + wv;
    short* vt = value_t + ((size_t)(b * 4096 + h_out * 64)) * 256 + cot * 64;
#pragma unroll
    for (int reg = 0; reg < 16; ++reg) {
        int m = (reg & 3) + 8 * (reg >> 2) + 4 * kh2;
        vt[(size_t)m * 256 + ln]             = f2bf(acc00[reg]);
        vt[(size_t)m * 256 + 32 + ln]        = f2bf(acc01[reg]);
        vt[(size_t)(m + 32) * 256 + ln]      = f2bf(acc10[reg]);
        vt[(size_t)(m + 32) * 256 + 32 + ln] = f2bf(acc11[reg]);
    }
}

// ------------- bf16 NT-GEMM: C[M,N]fp32 = A[M,K] @ B[N,K]^T -----------------
// Fragments loaded directly from global (both operands K-contiguous).
// Block 128 thr = 2 waves; block tile 64m x 128n; wave: 32m x 4 n-tiles.
// Supports K-split: blockIdx.x = kslice * tilesXY + tile; partial C written
// at C + kslice*sKsl (pass sKsl=0, tilesXY=grid for no split).
__global__ __launch_bounds__(128) void gemm_nt_bf16(const short* __restrict__ A,
                                                    const short* __restrict__ B,
                                                    float* __restrict__ C,
                                                    int Kld, int Ksub,
                                                    long sA, long sB, long sC,
                                                    int ldc, int tilesN, int tilesXY,
                                                    long sKsl) {
    const int kslice = blockIdx.x / tilesXY;
    const int t = blockIdx.x - kslice * tilesXY;
    const int mt = t / tilesN, nt = t - (t / tilesN) * tilesN;
    A += (size_t)blockIdx.y * sA;
    B += (size_t)blockIdx.y * sB;
    C += (size_t)blockIdx.y * sC + (size_t)kslice * sKsl;
    const int wv = threadIdx.x >> 6, l = threadIdx.x & 63;
    const int ln = l & 31, kh = l >> 5;
    const int kbase = kslice * Ksub;
    const short* arow = A + (size_t)(mt * 64 + wv * 32 + ln) * Kld + kbase + kh * 8;
    const short* brow = B + (size_t)(nt * 128 + ln) * Kld + kbase + kh * 8;
    floatx16 acc0 = {}, acc1 = {}, acc2 = {}, acc3 = {};
#pragma unroll 2
    for (int k0 = 0; k0 < Ksub; k0 += 16) {
        short8 a  = *(const short8*)&arow[k0];
        short8 b0 = *(const short8*)&brow[k0];
        short8 b1 = *(const short8*)&brow[(size_t)32 * Kld + k0];
        short8 b2 = *(const short8*)&brow[(size_t)64 * Kld + k0];
        short8 b3 = *(const short8*)&brow[(size_t)96 * Kld + k0];
        acc0 = __builtin_amdgcn_mfma_f32_32x32x16_bf16(a, b0, acc0, 0, 0, 0);
        acc1 = __builtin_amdgcn_mfma_f32_32x32x16_bf16(a, b1, acc1, 0, 0, 0);
        acc2 = __builtin_amdgcn_mfma_f32_32x32x16_bf16(a, b2, acc2, 0, 0, 0);
        acc3 = __builtin_amdgcn_mfma_f32_32x32x16_bf16(a, b3, acc3, 0, 0, 0);
    }
    const int n0 = nt * 128;
#pragma unroll
    for (int reg = 0; reg < 16; ++reg) {
        int m = mt * 64 + wv * 32 + (reg & 3) + 8 * (reg >> 2) + 4 * kh;
        float* crow = C + (size_t)m * ldc + n0 + ln;
        crow[0]  = acc0[reg];
        crow[32] = acc1[reg];
        crow[64] = acc2[reg];
        crow[96] = acc3[reg];
    }
}

// ---------------- fp32 GEMM 64x64 (kept for tiny attn2), opt bf16 out -------
template <int BT, int OB>
__global__ __launch_bounds__(256) void gemm64(const float* __restrict__ A,
                                              const float* __restrict__ B,
                                              float* __restrict__ C, int K,
                                              long sA, long sB, long sC,
                                              int ldA, int ldB, int ldC, int tilesN) {
    const int m0 = (blockIdx.x / tilesN) * 64;
    const int n0 = (blockIdx.x % tilesN) * 64;
    A += (size_t)blockIdx.y * sA;
    B += (size_t)blockIdx.y * sB;
    const size_t coff = (size_t)blockIdx.y * sC;
    __shared__ float As[16][68], Bs[16][68];
    const int tid = threadIdx.x;
    const int tx = tid & 15, ty = tid >> 4;
    const int mm = tid >> 2, kk4 = (tid & 3) * 4;
    float acc[4][4] = {};

    for (int k0 = 0; k0 < K; k0 += 16) {
        __syncthreads();
        {
            float4 a = *(const float4*)&A[(size_t)(m0 + mm) * ldA + k0 + kk4];
            As[kk4 + 0][mm] = a.x; As[kk4 + 1][mm] = a.y;
            As[kk4 + 2][mm] = a.z; As[kk4 + 3][mm] = a.w;
        }
        if (BT) {
            float4 bv = *(const float4*)&B[(size_t)(n0 + mm) * ldB + k0 + kk4];
            Bs[kk4 + 0][mm] = bv.x; Bs[kk4 + 1][mm] = bv.y;
            Bs[kk4 + 2][mm] = bv.z; Bs[kk4 + 3][mm] = bv.w;
        } else {
            int bk = tid >> 4, bn = (tid & 15) * 4;
            *(float4*)&Bs[bk][bn] = *(const float4*)&B[(size_t)(k0 + bk) * ldB + n0 + bn];
        }
        __syncthreads();
#pragma unroll
        for (int kk = 0; kk < 16; kk++) {
            float4 a = *(float4*)&As[kk][ty * 4];
            float4 bv = *(float4*)&Bs[kk][tx * 4];
            float av[4] = {a.x, a.y, a.z, a.w};
            float bb[4] = {bv.x, bv.y, bv.z, bv.w};
#pragma unroll
            for (int i = 0; i < 4; i++)
#pragma unroll
                for (int j = 0; j < 4; j++) acc[i][j] += av[i] * bb[j];
        }
    }
#pragma unroll
    for (int i = 0; i < 4; i++) {
        if (OB) {
            short* Cs = (short*)C + coff;
            short4 o;
            o.x = f2bf(acc[i][0]); o.y = f2bf(acc[i][1]);
            o.z = f2bf(acc[i][2]); o.w = f2bf(acc[i][3]);
            *(short4*)&Cs[(size_t)(m0 + ty * 4 + i) * ldC + n0 + tx * 4] = o;
        } else {
            float* Cf = (float*)C + coff;
            float4 o = make_float4(acc[i][0], acc[i][1], acc[i][2], acc[i][3]);
            *(float4*)&Cf[(size_t)(m0 + ty * 4 + i) * ldC + n0 + tx * 4] = o;
        }
    }
}

// -------- softmax over last dim (256): sum KSPLIT partials + scale + bias ---
__global__ __launch_bounds__(256) void softmax_kernel(float* __restrict__ sim,
                                                      const float* __restrict__ part,
                                                      const float* __restrict__ rm) {
    int row  = blockIdx.x * 4 + (threadIdx.x >> 6);
    int lane = threadIdx.x & 63;
    int c = row & 255;
    const size_t off = (size_t)row * 256 + lane * 4;
    const size_t sP = (size_t)NB * NC * NC;
    float4 v  = *(const float4*)&part[off];
    float4 p1 = *(const float4*)&part[off + sP];
    float4 p2 = *(const float4*)&part[off + 2 * sP];
    float4 p3 = *(const float4*)&part[off + 3 * sP];
    v.x += p1.x + p2.x + p3.x;
    v.y += p1.y + p2.y + p3.y;
    v.z += p1.z + p2.z + p3.z;
    v.w += p1.w + p2.w + p3.w;
    const float4 bias = *(const float4*)&rm[c * 256 + lane * 4];
    v.x = v.x * 0.0625f + bias.x;
    v.y = v.y * 0.0625f + bias.y;
    v.z = v.z * 0.0625f + bias.z;
    v.w = v.w * 0.0625f + bias.w;
    float m = fmaxf(fmaxf(v.x, v.y), fmaxf(v.z, v.w));
#pragma unroll
    for (int off2 = 32; off2 > 0; off2 >>= 1) m = fmaxf(m, __shfl_xor(m, off2, 64));
    float e0 = __expf(v.x - m), e1 = __expf(v.y - m);
    float e2 = __expf(v.z - m), e3 = __expf(v.w - m);
    float s = e0 + e1 + e2 + e3;
#pragma unroll
    for (int off2 = 32; off2 > 0; off2 >>= 1) s += __shfl_xor(s, off2, 64);
    float inv = 1.f / s;
    float4 o = make_float4(e0 * inv, e1 * inv, e2 * inv, e3 * inv);
    *(float4*)&sim[off] = o;
}

extern "C" void kernel_launch(void* const* d_in, const int* in_sizes, int n_in,
                              void* d_out, int out_size, void* d_ws, size_t ws_size,
                              hipStream_t stream) {
    const float* x     = (const float*)d_in[0];
    const float* x_mid = (const float*)d_in[1];
    const float* g_w   = (const float*)d_in[2];
    const float* w_w   = (const float*)d_in[3];
    const float* w1    = (const float*)d_in[4];
    const float* w2    = (const float*)d_in[5];
    float* out = (float*)d_out;

    char* ws = (char*)d_ws;
    short* value_t = (short*)ws;                                   // 67.1 MB [b][px][co]
    float* sim     = (float*)(ws + (size_t)NB * NPIX * NC * 2);    // 8.4 MB
    short* attn2_b = (short*)(sim + (size_t)NB * NC * NC);         // 4.2 MB [b][co][d]
    float* rm      = (float*)(attn2_b + (size_t)NB * NC * NC);     // 0.26 MB
    short* xt      = (short*)(rm + NC * NC);                       // 67.1 MB
    short* xb      = xt + (size_t)NB * NPIX * NC;                  // 67.1 MB
    short* wt      = xb + (size_t)NB * NC * NPIX;                  // 1.18 MB

    // sim partials live in d_out (134 MB, dead until the final GEMM rewrites it)
    float* simPart = out;

    cvt_w_kernel<<<288, 256, 0, stream>>>(g_w, wt);
    cvt_x_kernel<<<dim3(64, 32), 256, 0, stream>>>(x_mid, xt);
    cvt_bf16_kernel<<<16384, 256, 0, stream>>>(x, xb);
    rm_kernel<<<256, 256, 0, stream>>>(w1, w2, rm);
    // value_t[b][px][co] = conv3x3(x_mid, g_w)
    conv_mfma<<<dim3(16, 4, 32), 256, 0, stream>>>(xt, wt, value_t);
    // simPart[p] = xb @ xb^T over K-slice p  (M=N=256, K=4096, 4-way K-split)
    gemm_nt_bf16<<<dim3(8 * KSPLIT, 32), 128, 0, stream>>>(
        xb, xb, simPart, 4096, 4096 / KSPLIT,
        (long)NC * NPIX, (long)NC * NPIX, (long)NC * NC, NC, 2, 8,
        (long)NB * NC * NC);
    softmax_kernel<<<2048, 256, 0, stream>>>(sim, simPart, rm);
    // attn2_b = bf16(w_w @ attn)  (M=N=K=256; A not batched)
    gemm64<0, 1><<<dim3(16, 32), 256, 0, stream>>>(
        w_w, sim, (float*)attn2_b, 256,
        0L, (long)NC * NC, (long)NC * NC,
        NC, NC, NC, 4);
    // out[b][co][px] = attn2_b @ value_t^T  (M=256, N=4096, K=256)
    gemm_nt_bf16<<<dim3(128, 32), 128, 0, stream>>>(
        attn2_b, value_t, out, 256, 256,
        (long)NC * NC, (long)NPIX * NC, (long)NC * NPIX, NPIX, 32, 128, 0L);
}